// Round 10
// baseline (577.075 us; speedup 1.0000x reference)
//
#include <hip/hip_runtime.h>
#include <math.h>
#include <stdint.h>

// MultipleTopoTreeLoss = mean over 32 (sample,chunk) pairs of sum of squared
// Euclidean-MST edge lengths of 1024 standardized 3-D points.  Boruvka,
// ONE worker kernel launch + one 4KiB memset.
//
// r8 post-mortem: no-clear/targeted-flush + poll barrier + folded combine
// regressed 138->180us/kernel (dup global atomics: WRITE_SIZE 1.9->4.5MB).
// r9/r10 = r5's proven per-round pieces (Wl clear, sweep flush, double-
// buffered winners, tags) + structural overlap:
//   - 512 blocks x 512 thr: CU k hosts TWO blocks from DIFFERENT samples
//     (s = ((b&31)+(b>>8)*8)&31, part = ((b>>5)&7)|(b>>8)*8).  A sample's 16
//     parts all satisfy b == s (mod 8) -> one XCD (L2-local barrier+winners),
//     while each CU's two blocks have independent barriers -> one sample's
//     sync/combine overhead hides under the other's scan.
//   - epoch flag barrier (monotone, contention-free); flags explicitly
//     zeroed by hipMemsetAsync (NOT relying on harness poison semantics);
//     winner tables cleared in-kernel behind the entry barrier; block 0
//     gathers per-sample totals by polling part-0 final flags.
// Key = (15-rd)<<60 | d2bits<<20 | min(i,j)<<10 | max(i,j): decreasing tags
// let current-round keys win atomicMin over stale entries (no global clears
// after the initial one).  Symmetric distinct keys => total edge order =>
// hooking graph has only 2-cycles; dedupe by key equality; 2-cycle break
// folded into the root chase (next==prev -> root=min).  absmax 0 in r2-r8.
// Deadlock audit: 512 blocks x 8 waves x 28KiB -> capacity 4/CU, 1024 >= 512
// so all blocks always resident; 2-round parity separation proven by epoch
// induction; exit uniform (deterministic redundant combine).

#define NSAMP   32
#define NPTS    1024
#define SBLK    16
#define NPN     64          // nodes per part (16 parts x 64 = 1024)
#define TPB     512
#define MAXRD   11
#define FINAL_EPOCH 1000
#define EMPTY64 0xFFFFFFFFFFFFFFFFull

typedef unsigned long long u64;

__device__ __forceinline__ u64 aload64(const u64* p) {
  return __hip_atomic_load(p, __ATOMIC_RELAXED, __HIP_MEMORY_SCOPE_AGENT);
}
__device__ __forceinline__ void astore64(u64* p, u64 v) {
  __hip_atomic_store(p, v, __ATOMIC_RELAXED, __HIP_MEMORY_SCOPE_AGENT);
}

// block-wide sum of two floats (512 threads = 8 waves)
__device__ __forceinline__ void block_sum2(float& a, float& b, float* red) {
#pragma unroll
  for (int off = 32; off > 0; off >>= 1) {
    a += __shfl_xor(a, off, 64);
    b += __shfl_xor(b, off, 64);
  }
  __syncthreads();
  const int wid = threadIdx.x >> 6;
  if ((threadIdx.x & 63) == 0) { red[wid * 2] = a; red[wid * 2 + 1] = b; }
  __syncthreads();
  float ra = 0.f, rb = 0.f;
#pragma unroll
  for (int k = 0; k < 8; ++k) { ra += red[k * 2]; rb += red[k * 2 + 1]; }
  a = ra; b = rb;
}

// epoch barrier among one sample's 16 blocks: store own epoch (release),
// wait until all >= epoch.  Monotone epochs -> no reset needed.
__device__ __forceinline__ void fbar(int* fl, int part, int epoch) {
  __syncthreads();
  if (threadIdx.x == 0) {
    __hip_atomic_store(&fl[part], epoch, __ATOMIC_RELEASE,
                       __HIP_MEMORY_SCOPE_AGENT);
    for (;;) {
      int mn = 0x7fffffff;
#pragma unroll
      for (int b2 = 0; b2 < SBLK; ++b2) {
        const int v = __hip_atomic_load(&fl[b2], __ATOMIC_ACQUIRE,
                                        __HIP_MEMORY_SCOPE_AGENT);
        mn = v < mn ? v : mn;
      }
      if (mn >= epoch) break;
      __builtin_amdgcn_s_sleep(1);
    }
  }
  __syncthreads();
}

__global__ __launch_bounds__(TPB) void topo_kernel(
    const float* __restrict__ r, u64* __restrict__ gw, int* __restrict__ flags,
    float* __restrict__ totals, float* __restrict__ out) {
  const int hi   = blockIdx.x >> 8;                        // 0 or 1
  const int s    = ((blockIdx.x & 31) + (hi << 3)) & 31;   // sample
  const int part = ((blockIdx.x >> 5) & 7) | (hi << 3);    // 0..15
  const int tid  = threadIdx.x;
  const int i0 = tid, i1 = tid + TPB;

  __shared__ float4 P[NPTS];          // 16 KiB: xyz + comp-label bits in .w
  __shared__ u64 Wl[NPTS];            // 8 KiB
  __shared__ short parentL[NPTS];     // 2 KiB
  __shared__ float red[16];

  int* fl = flags + s * 32;
  u64* __restrict__ gws0 = gw + s * NPTS;
  u64* __restrict__ gws1 = gw + (NSAMP + s) * NPTS;

  // ---- standardize (redundant per block; bitwise-identical) ----
  const float* __restrict__ base = r + (size_t)s * (NPTS * 3);
  const float ax = base[i0 * 3 + 0], ay = base[i0 * 3 + 1], az = base[i0 * 3 + 2];
  const float bx = base[i1 * 3 + 0], by = base[i1 * 3 + 1], bz = base[i1 * 3 + 2];
  float sx = ax + bx, sy = ay + by, sz = az + bz, dm = 0.f;
  block_sum2(sx, sy, red); block_sum2(sz, dm, red);
  const float mx = sx * (1.f / NPTS), my = sy * (1.f / NPTS), mz = sz * (1.f / NPTS);
  const float ex0 = ax - mx, ey0 = ay - my, ez0 = az - mz;
  const float ex1 = bx - mx, ey1 = by - my, ez1 = bz - mz;
  float vx = ex0 * ex0 + ex1 * ex1, vy = ey0 * ey0 + ey1 * ey1,
        vz = ez0 * ez0 + ez1 * ez1;
  dm = 0.f;
  block_sum2(vx, vy, red); block_sum2(vz, dm, red);
  const float ix = 1.f / (sqrtf(vx * (1.f / NPTS)) + 1e-8f);
  const float iy = 1.f / (sqrtf(vy * (1.f / NPTS)) + 1e-8f);
  const float iz = 1.f / (sqrtf(vz * (1.f / NPTS)) + 1e-8f);
  P[i0] = make_float4(ex0 * ix, ey0 * iy, ez0 * iz, __uint_as_float((unsigned)i0));
  P[i1] = make_float4(ex1 * ix, ey1 * iy, ez1 * iz, __uint_as_float((unsigned)i1));

  // ---- one-time clear of this part's slice of both winner buffers ----
  if (tid < NPN) {
    astore64(&gws0[part * NPN + tid], EMPTY64);
    astore64(&gws1[part * NPN + tid], EMPTY64);
  }
  fbar(fl, part, 1);                  // clears visible before any flush

  float total = 0.f;                  // block-uniform after each round
  const int g  = tid >> 5, sl = tid & 31;
  const int n0 = part * NPN + g * 4;  // 16 groups x 4 nodes = 64 nodes/part

  for (int rd = 0; rd < MAXRD; ++rd) {
    u64* __restrict__ gwc = (rd & 1) ? gws1 : gws0;
    const u64 tag = (u64)(15 - rd) << 60;   // decreasing: current wins min

    Wl[i0] = EMPTY64; Wl[i1] = EMPTY64;     // per-round clear (r5-proven)
    __syncthreads();

    // ---- scan: 4 nodes x 32 candidates per thread ----
    float mex[4], mey[4], mez[4]; unsigned mc[4];
#pragma unroll
    for (int n = 0; n < 4; ++n) {
      const float4 p = P[n0 + n];
      mex[n] = p.x; mey[n] = p.y; mez[n] = p.z; mc[n] = __float_as_uint(p.w);
    }
    float bd[4]; int bj[4];
#pragma unroll
    for (int n = 0; n < 4; ++n) { bd[n] = INFINITY; bj[n] = n0 + n; }
#pragma unroll 8
    for (int jj = 0; jj < 32; ++jj) {
      const int j = sl + (jj << 5);
      const float4 q = P[j];          // lanes l, l+32 share addr: broadcast
      const unsigned qc = __float_as_uint(q.w);
#pragma unroll
      for (int n = 0; n < 4; ++n) {
        const float dx = mex[n] - q.x, dy = mey[n] - q.y, dz = mez[n] - q.z;
        float d2 = dx * dx + dy * dy + dz * dz;
        d2 = (qc == mc[n]) ? INFINITY : d2;
        if (d2 < bd[n]) { bd[n] = d2; bj[n] = j; }
      }
    }
#pragma unroll
    for (int off = 16; off > 0; off >>= 1) {    // reduce 32 sub-lanes
#pragma unroll
      for (int n = 0; n < 4; ++n) {
        const float od = __shfl_xor(bd[n], off, 64);
        const int   oj = __shfl_xor(bj[n], off, 64);
        if (od < bd[n] || (od == bd[n] && oj < bj[n])) { bd[n] = od; bj[n] = oj; }
      }
    }
    if (sl == 0) {                    // per-comp LDS pre-reduce
#pragma unroll
      for (int n = 0; n < 4; ++n) {
        const int node = n0 + n, j = bj[n];
        const unsigned a = (unsigned)(node < j ? node : j);
        const unsigned b = (unsigned)(node < j ? j : node);
        const u64 key = tag | ((u64)__float_as_uint(bd[n]) << 20)
                      | (a << 10) | b;
        atomicMin(&Wl[mc[n]], key);
      }
    }
    __syncthreads();
    { // sweep-flush non-empty local winners (<=64 per block)
      const u64 w0 = Wl[i0], w1 = Wl[i1];
      if (w0 != EMPTY64) atomicMin(&gwc[i0], w0);
      if (w1 != EMPTY64) atomicMin(&gwc[i1], w1);
    }
    fbar(fl, part, rd + 2);           // all flushes of this round visible

    // ---- combine (redundant per block; deterministic) ----
    const u64 w0 = aload64(&gwc[i0]);
    const u64 w1 = aload64(&gwc[i1]);
    Wl[i0] = w0; Wl[i1] = w1;
    __syncthreads();
    const unsigned curtag = (unsigned)(15 - rd);
    float wadd = 0.f;
    short par0 = (short)i0, par1 = (short)i1;
    if ((unsigned)(w0 >> 60) == curtag) {
      const int pmin = (int)((w0 >> 10) & 1023u);
      const int pmax = (int)(w0 & 1023u);
      const int cmin = (int)__float_as_uint(P[pmin].w);
      const int cmax = (int)__float_as_uint(P[pmax].w);
      const int c2 = (cmin == i0) ? cmax : cmin;
      par0 = (short)c2;
      const bool dup = (Wl[c2] == w0);
      if (!dup || i0 < c2)
        wadd += __uint_as_float((unsigned)((w0 >> 20) & 0xFFFFFFFFull));
    }
    if ((unsigned)(w1 >> 60) == curtag) {
      const int pmin = (int)((w1 >> 10) & 1023u);
      const int pmax = (int)(w1 & 1023u);
      const int cmin = (int)__float_as_uint(P[pmin].w);
      const int cmax = (int)__float_as_uint(P[pmax].w);
      const int c2 = (cmin == i1) ? cmax : cmin;
      par1 = (short)c2;
      const bool dup = (Wl[c2] == w1);
      if (!dup || i1 < c2)
        wadd += __uint_as_float((unsigned)((w1 >> 20) & 0xFFFFFFFFull));
    }
    parentL[i0] = par0; parentL[i1] = par1;
    __syncthreads();
    // chase to root, 2-cycle break inline (next==prev -> root = min)
    int c0 = (int)__float_as_uint(P[i0].w);
    {
      int prev = -1, p = c0;
      for (int it = 0; it < 1024; ++it) {
        const int nx = parentL[p];
        if (nx == p) break;
        if (nx == prev) { p = p < prev ? p : prev; break; }
        prev = p; p = nx;
      }
      c0 = p;
    }
    int c1 = (int)__float_as_uint(P[i1].w);
    {
      int prev = -1, p = c1;
      for (int it = 0; it < 1024; ++it) {
        const int nx = parentL[p];
        if (nx == p) break;
        if (nx == prev) { p = p < prev ? p : prev; break; }
        prev = p; p = nx;
      }
      c1 = p;
    }
    float fc = (c0 == i0 ? 1.f : 0.f) + (c1 == i1 ? 1.f : 0.f);
    block_sum2(wadd, fc, red);        // block-uniform results
    total += wadd;
    P[i0].w = __uint_as_float((unsigned)c0);
    P[i1].w = __uint_as_float((unsigned)c1);
    if (fc == 1.f) break;             // deterministic -> uniform across parts
    __syncthreads();                  // label writes visible to next scan
  }

  // ---- publish per-sample total; block 0 gathers ----
  if (tid == 0) {
    if (part == 0)
      __hip_atomic_store(&totals[s], total, __ATOMIC_RELAXED,
                         __HIP_MEMORY_SCOPE_AGENT);
    __hip_atomic_store(&fl[part], FINAL_EPOCH, __ATOMIC_RELEASE,
                       __HIP_MEMORY_SCOPE_AGENT);
  }
  if (blockIdx.x == 0 && tid == 0) {  // s==0, part==0
    float t = 0.f;
    for (int ss = 0; ss < NSAMP; ++ss) {
      while (__hip_atomic_load(&flags[ss * 32], __ATOMIC_ACQUIRE,
                               __HIP_MEMORY_SCOPE_AGENT) < FINAL_EPOCH) {
        __builtin_amdgcn_s_sleep(1);
      }
      t += __hip_atomic_load(&totals[ss], __ATOMIC_RELAXED,
                             __HIP_MEMORY_SCOPE_AGENT);
    }
    out[0] = t * (1.f / NSAMP);
  }
}

extern "C" void kernel_launch(void* const* d_in, const int* in_sizes, int n_in,
                              void* d_out, int out_size, void* d_ws, size_t ws_size,
                              hipStream_t stream) {
  const float* r = (const float*)d_in[0];
  float* out = (float*)d_out;
  (void)in_sizes; (void)n_in; (void)out_size; (void)ws_size;

  char* ws = (char*)d_ws;
  int*   flags  = (int*)ws;                     // 32 x 128 B
  float* totals = (float*)(ws + 4096);          // 32 floats
  u64*   gw     = (u64*)(ws + 8192);            // 2 x 32 x 1024 x 8 B

  hipMemsetAsync(ws, 0, 8192, stream);          // flags + totals (explicit)
  topo_kernel<<<dim3(NSAMP * SBLK), dim3(TPB), 0, stream>>>(
      r, gw, flags, totals, out);
}

// Round 11
// 145.601 us; speedup vs baseline: 3.9634x; 3.9634x over previous
//
#include <hip/hip_runtime.h>
#include <math.h>
#include <stdint.h>

// MultipleTopoTreeLoss = mean over 32 (sample,chunk) pairs of sum of squared
// Euclidean-MST edge lengths of 1024 standardized 3-D points.  Boruvka.
//
// r10 post-mortem: poll-all flag barrier = 557us (VALU work unchanged vs r5;
// all regression = waiting).  Harness poisons the 256MB ws every replay
// (~40us fill in-graph) -> every config pays ~45us fixed; r3's multi-launch
// (115us net) still beats every persistent attempt (r5 = 138 net) because
// kernel-boundary sync (~1us/gap) is cheaper than any in-kernel cross-CU
// barrier (~9us/round residual).  Scan is throughput-bound (~4.3us/round,
// 33.5M evals over 256 CUs) regardless of geometry.
//
// This round: FUSE combine(rd-1)+scan(rd) per kernel.  12 dispatches:
//   k0:    norm (redundant/block, bitwise-identical) + publish pts4 (part0)
//          + clear own slice of BOTH winner buffers + scan round 0 + flush.
//          Round-0 flush targets only the block's own 128 slots (comp==node),
//          so same-kernel clear->atomicMin is safe (syncthreads drains vmcnt).
//   fused rd=1..10: early-exit if sample done; stage coords+winners+labels;
//          redundant-per-block combine (hook, dedupe-by-key, chase with
//          inline 2-cycle break) -> new labels; part0 stores labels/totals/
//          ncomp; if done return; scan(rd); flush to parity buffer rd&1.
//   finish: mean of 32 totals.
// Zero memsets: every word written-before-read across the dispatch chain
// (poison-immune).  Key = (15-rd)<<60 | d2bits<<20 | min<<10 | max:
// decreasing tags make stale parity-buffer entries lose atomicMin (no
// per-round clears).  All compute bodies verbatim from the 138us r5 kernel
// (absmax 0 in r2-r10).

#define NSAMP   32
#define NPTS    1024
#define SBLK    8
#define NPN     128
#define TPB     1024
#define NROUNDS 10          // Boruvka on 1024 nodes needs <=10 rounds
#define EMPTY64 0xFFFFFFFFFFFFFFFFull

typedef unsigned long long u64;
typedef unsigned short u16;

__device__ __forceinline__ void block_sum2(float& a, float& b, float* red) {
#pragma unroll
  for (int off = 32; off > 0; off >>= 1) {
    a += __shfl_xor(a, off, 64);
    b += __shfl_xor(b, off, 64);
  }
  __syncthreads();
  const int wid = threadIdx.x >> 6;
  if ((threadIdx.x & 63) == 0) { red[wid * 2] = a; red[wid * 2 + 1] = b; }
  __syncthreads();
  float ra = 0.f, rb = 0.f;
#pragma unroll
  for (int k = 0; k < 16; ++k) { ra += red[k * 2]; rb += red[k * 2 + 1]; }
  a = ra; b = rb;
}

// r5-verbatim scan: 4 nodes x 32 candidates per thread, 5-step shfl argmin,
// per-comp LDS atomicMin of tagged key (deterministic: key total-orders edges).
__device__ __forceinline__ void boruvka_scan(const float4* P, u64* Wl,
                                             int part, int tid, u64 tag) {
  const int g = tid >> 5, sl = tid & 31;
  const int n0 = part * NPN + g * 4;
  float mex[4], mey[4], mez[4]; unsigned mc[4];
#pragma unroll
  for (int n = 0; n < 4; ++n) {
    const float4 p = P[n0 + n];
    mex[n] = p.x; mey[n] = p.y; mez[n] = p.z; mc[n] = __float_as_uint(p.w);
  }
  float bd[4]; int bj[4];
#pragma unroll
  for (int n = 0; n < 4; ++n) { bd[n] = INFINITY; bj[n] = n0 + n; }
#pragma unroll 8
  for (int jj = 0; jj < 32; ++jj) {
    const int j = sl + (jj << 5);
    const float4 q = P[j];            // lanes l, l+32 share addr: broadcast
    const unsigned qc = __float_as_uint(q.w);
#pragma unroll
    for (int n = 0; n < 4; ++n) {
      const float dx = mex[n] - q.x, dy = mey[n] - q.y, dz = mez[n] - q.z;
      float d2 = dx * dx + dy * dy + dz * dz;
      d2 = (qc == mc[n]) ? INFINITY : d2;
      if (d2 < bd[n]) { bd[n] = d2; bj[n] = j; }
    }
  }
#pragma unroll
  for (int off = 16; off > 0; off >>= 1) {      // reduce 32 sub-lanes
#pragma unroll
    for (int n = 0; n < 4; ++n) {
      const float od = __shfl_xor(bd[n], off, 64);
      const int   oj = __shfl_xor(bj[n], off, 64);
      if (od < bd[n] || (od == bd[n] && oj < bj[n])) { bd[n] = od; bj[n] = oj; }
    }
  }
  if (sl == 0) {
#pragma unroll
    for (int n = 0; n < 4; ++n) {
      if (bd[n] < INFINITY) {
        const int node = n0 + n, j = bj[n];
        const unsigned a = (unsigned)(node < j ? node : j);
        const unsigned b = (unsigned)(node < j ? j : node);
        const u64 key = tag | ((u64)__float_as_uint(bd[n]) << 20)
                      | (a << 10) | b;
        atomicMin(&Wl[mc[n]], key);
      }
    }
  }
}

// ---- k0: norm + publish pts + clear winner slices + scan round 0 ----------
__global__ __launch_bounds__(TPB) void topo_k0(
    const float* __restrict__ r, float4* __restrict__ pts4,
    u64* __restrict__ gw) {
  const int s = blockIdx.x & 31, part = blockIdx.x >> 5, tid = threadIdx.x;
  __shared__ float4 P[NPTS];
  __shared__ u64 Wl[NPTS];
  __shared__ float red[32];

  const float* __restrict__ base = r + (size_t)s * (NPTS * 3);
  const float px = base[tid * 3 + 0];
  const float py = base[tid * 3 + 1];
  const float pz = base[tid * 3 + 2];
  float sx = px, sy = py, sz = pz, dm = 0.f;
  block_sum2(sx, sy, red); block_sum2(sz, dm, red);
  const float mx = sx * (1.f / NPTS), my = sy * (1.f / NPTS), mz = sz * (1.f / NPTS);
  const float ex = px - mx, ey = py - my, ez = pz - mz;
  float vx = ex * ex, vy = ey * ey, vz = ez * ez;
  dm = 0.f;
  block_sum2(vx, vy, red); block_sum2(vz, dm, red);
  const float ix = 1.f / (sqrtf(vx * (1.f / NPTS)) + 1e-8f);
  const float iy = 1.f / (sqrtf(vy * (1.f / NPTS)) + 1e-8f);
  const float iz = 1.f / (sqrtf(vz * (1.f / NPTS)) + 1e-8f);
  const float4 pv =
      make_float4(ex * ix, ey * iy, ez * iz, __uint_as_float((unsigned)tid));
  P[tid] = pv;
  if (part == 0) pts4[(size_t)s * NPTS + tid] = pv;
  if (tid < NPN) {                      // clear own slice, BOTH parities
    gw[(size_t)s * NPTS + part * NPN + tid] = EMPTY64;
    gw[(size_t)(NSAMP + s) * NPTS + part * NPN + tid] = EMPTY64;
  }
  Wl[tid] = EMPTY64;
  __syncthreads();                      // drains stores before atomics

  boruvka_scan(P, Wl, part, tid, (u64)15 << 60);   // labels = identity
  __syncthreads();
  const u64 w = Wl[tid];                // round 0: non-EMPTY only in own slice
  if (w != EMPTY64) atomicMin(&gw[(size_t)s * NPTS + tid], w);
}

// ---- fused: combine(rd-1) + scan(rd) --------------------------------------
__global__ __launch_bounds__(TPB) void topo_fused(
    const float4* __restrict__ pts4, u64* __restrict__ gw,
    u16* __restrict__ glab, int* __restrict__ ncomp,
    float* __restrict__ totals, int rd) {
  const int s = blockIdx.x & 31, part = blockIdx.x >> 5, tid = threadIdx.x;
  if (rd >= 2 && ncomp[s] == 1) return;     // sample finished earlier
  __shared__ float4 P[NPTS];            // 16 KiB
  __shared__ u64 Wl[NPTS];              // 8 KiB
  __shared__ u16 oldlab[NPTS];          // 2 KiB
  __shared__ short parentL[NPTS];       // 2 KiB
  __shared__ float red[32];

  const u64* __restrict__ gwp =
      gw + (size_t)(((rd - 1) & 1) ? (NSAMP + s) : s) * NPTS;
  u64* __restrict__ gwc = gw + (size_t)((rd & 1) ? (NSAMP + s) : s) * NPTS;

  const float4 pc = pts4[(size_t)s * NPTS + tid];   // coords (w ignored)
  const u64 w = gwp[tid];               // plain load: boundary-coherent
  Wl[tid] = w;
  oldlab[tid] = (rd == 1) ? (u16)tid : glab[s * NPTS + tid];
  __syncthreads();

  // combine slot tid (comp id), redundant per block, deterministic
  const unsigned curtag = (unsigned)(16 - rd);      // 15 - (rd-1)
  float wadd = 0.f;
  short par = (short)tid;
  if ((unsigned)(w >> 60) == curtag) {
    const int pmin = (int)((w >> 10) & 1023u);
    const int pmax = (int)(w & 1023u);
    const int cmin = oldlab[pmin], cmax = oldlab[pmax];
    const int c2 = (cmin == tid) ? cmax : cmin;
    par = (short)c2;
    const bool dup = (Wl[c2] == w);     // same undirected edge <=> same key
    if (!dup || tid < c2)
      wadd = __uint_as_float((unsigned)((w >> 20) & 0xFFFFFFFFull));
  }
  parentL[tid] = par;
  __syncthreads();
  // chase to root, inline 2-cycle break (next==prev -> root = min)
  int c = oldlab[tid];
  {
    int prev = -1, p = c;
    for (int it = 0; it < 1024; ++it) {
      const int nx = parentL[p];
      if (nx == p) break;
      if (nx == prev) { p = p < prev ? p : prev; break; }
      prev = p; p = nx;
    }
    c = p;
  }
  float fc = (c == tid) ? 1.f : 0.f;    // one root-node per component
  block_sum2(wadd, fc, red);
  P[tid] = make_float4(pc.x, pc.y, pc.z, __uint_as_float((unsigned)c));
  if (part == 0) {
    glab[s * NPTS + tid] = (u16)c;
    if (tid == 0) {
      totals[s] = (rd == 1 ? 0.f : totals[s]) + wadd;
      ncomp[s] = (int)fc;
    }
  }
  if (fc == 1.f) return;                // done: skip scan (uniform)

  Wl[tid] = EMPTY64;
  __syncthreads();
  boruvka_scan(P, Wl, part, tid, (u64)(15 - rd) << 60);
  __syncthreads();
  const u64 wn = Wl[tid];
  if (wn != EMPTY64) atomicMin(&gwc[tid], wn);
}

// ---- finish ----------------------------------------------------------------
__global__ __launch_bounds__(64) void topo_finish(
    const float* __restrict__ totals, float* __restrict__ out) {
  float v = (threadIdx.x < NSAMP) ? totals[threadIdx.x] : 0.f;
#pragma unroll
  for (int off = 32; off > 0; off >>= 1) v += __shfl_xor(v, off, 64);
  if (threadIdx.x == 0) out[0] = v * (1.f / NSAMP);
}

extern "C" void kernel_launch(void* const* d_in, const int* in_sizes, int n_in,
                              void* d_out, int out_size, void* d_ws, size_t ws_size,
                              hipStream_t stream) {
  const float* r = (const float*)d_in[0];
  float* out = (float*)d_out;
  (void)in_sizes; (void)n_in; (void)out_size; (void)ws_size;

  char* ws = (char*)d_ws;               // ~1.1 MB used (ws is ~256 MB)
  float4* pts4  = (float4*)ws;                          // 512 KiB
  u64*    gw    = (u64*)(ws + 524288);                  // 512 KiB (2 parities)
  u16*    glab  = (u16*)(ws + 1048576);                 //  64 KiB
  int*    ncomp = (int*)(ws + 1114112);                 // 128 B
  float*  totals= (float*)(ws + 1118208);               // 128 B

  topo_k0<<<dim3(NSAMP * SBLK), dim3(TPB), 0, stream>>>(r, pts4, gw);
  for (int rd = 1; rd <= NROUNDS; ++rd) {
    topo_fused<<<dim3(NSAMP * SBLK), dim3(TPB), 0, stream>>>(
        pts4, gw, glab, ncomp, totals, rd);
  }
  topo_finish<<<dim3(1), dim3(64), 0, stream>>>(totals, out);
}